// Round 1
// baseline (1716.689 us; speedup 1.0000x reference)
//
#include <hip/hip_runtime.h>

#define N_NODES 10000
#define IN_DIM 256
#define HIDDEN 256
#define OUT_DIM 128
#define N_EDGES_MAX 320000

// C[M,N] = op(A)[M,K] @ B[K,N];  op = relu if RELU_A. BM=BN=64, BK=16, 4x4 microtile.
template<bool RELU_A>
__global__ __launch_bounds__(256)
void gemm_f32(const float* __restrict__ A, const float* __restrict__ B,
              float* __restrict__ C, int M, int N, int K) {
  constexpr int BM = 64, BN = 64, BK = 16;
  __shared__ float As[BM][BK + 1];
  __shared__ float Bs[BK][BN];
  const int tx = threadIdx.x & 15;   // N direction, 0..15
  const int ty = threadIdx.x >> 4;   // M direction, 0..15
  const int row0 = blockIdx.y * BM;
  const int col0 = blockIdx.x * BN;
  const int t = threadIdx.x;
  const int lm = t >> 2;             // A-load row 0..63
  const int lk = (t & 3) * 4;        // A-load k 0,4,8,12
  const int bk = t >> 4;             // B-load k 0..15
  const int bn = (t & 15) * 4;       // B-load n 0..60
  float acc[4][4] = {};
  for (int k0 = 0; k0 < K; k0 += BK) {
    int ar = row0 + lm;
    float4 av = make_float4(0.f, 0.f, 0.f, 0.f);
    if (ar < M) av = *reinterpret_cast<const float4*>(A + (size_t)ar * K + k0 + lk);
    if (RELU_A) {
      av.x = fmaxf(av.x, 0.f); av.y = fmaxf(av.y, 0.f);
      av.z = fmaxf(av.z, 0.f); av.w = fmaxf(av.w, 0.f);
    }
    As[lm][lk + 0] = av.x; As[lm][lk + 1] = av.y;
    As[lm][lk + 2] = av.z; As[lm][lk + 3] = av.w;
    float4 bv = *reinterpret_cast<const float4*>(B + (size_t)(k0 + bk) * N + col0 + bn);
    *reinterpret_cast<float4*>(&Bs[bk][bn]) = bv;
    __syncthreads();
#pragma unroll
    for (int kk = 0; kk < BK; ++kk) {
      float a[4], b[4];
#pragma unroll
      for (int i = 0; i < 4; ++i) a[i] = As[ty * 4 + i][kk];
#pragma unroll
      for (int j = 0; j < 4; ++j) b[j] = Bs[kk][tx * 4 + j];
#pragma unroll
      for (int i = 0; i < 4; ++i)
#pragma unroll
        for (int j = 0; j < 4; ++j)
          acc[i][j] = fmaf(a[i], b[j], acc[i][j]);
    }
    __syncthreads();
  }
#pragma unroll
  for (int i = 0; i < 4; ++i) {
    int r = row0 + ty * 4 + i;
    if (r < M) {
#pragma unroll
      for (int j = 0; j < 4; ++j)
        C[(size_t)r * N + col0 + tx * 4 + j] = acc[i][j];
    }
  }
}

// Z[dst] += val * X[src], D dims per edge, float4 per thread, atomic scatter.
template<int D>
__global__ __launch_bounds__(256)
void scatter_add(const float* __restrict__ X, const int* __restrict__ src,
                 const int* __restrict__ dst, const float* __restrict__ val,
                 float* __restrict__ Z, int nE) {
  constexpr int TPE = D / 4;  // threads per edge
  int gid = blockIdx.x * 256 + threadIdx.x;
  int e = gid / TPE;
  int lane = gid - e * TPE;
  if (e >= nE) return;
  int s = src[e];
  int d = dst[e];
  float v = val[e];
  float4 x = *reinterpret_cast<const float4*>(X + (size_t)s * D + lane * 4);
  float* zp = Z + (size_t)d * D + lane * 4;
  atomicAdd(zp + 0, v * x.x);
  atomicAdd(zp + 1, v * x.y);
  atomicAdd(zp + 2, v * x.z);
  atomicAdd(zp + 3, v * x.w);
}

extern "C" void kernel_launch(void* const* d_in, const int* in_sizes, int n_in,
                              void* d_out, int out_size, void* d_ws, size_t ws_size,
                              hipStream_t stream) {
  const float* features = (const float*)d_in[0];
  const int*   esrc     = (const int*)d_in[1];
  const int*   edst     = (const int*)d_in[2];
  const float* evalv    = (const float*)d_in[3];
  const float* W0       = (const float*)d_in[4];
  const float* W1       = (const float*)d_in[5];
  const int nE = in_sizes[1];
  float* out = (float*)d_out;

  float* T0 = (float*)d_ws;                          // [N_NODES, HIDDEN]
  float* Z  = T0 + (size_t)N_NODES * HIDDEN;         // [N_NODES, HIDDEN]
  float* T1 = Z  + (size_t)N_NODES * HIDDEN;         // [N_NODES, OUT_DIM]

  // T0 = F @ W0   (associativity: spmm(F) @ W0 == A @ (F @ W0))
  dim3 g1(HIDDEN / 64, (N_NODES + 63) / 64);
  gemm_f32<false><<<g1, 256, 0, stream>>>(features, W0, T0, N_NODES, HIDDEN, IN_DIM);

  // Z = A @ T0
  hipMemsetAsync(Z, 0, (size_t)N_NODES * HIDDEN * sizeof(float), stream);
  int nb1 = (nE * (HIDDEN / 4) + 255) / 256;
  scatter_add<HIDDEN><<<nb1, 256, 0, stream>>>(T0, esrc, edst, evalv, Z, nE);

  // T1 = relu(Z) @ W1
  dim3 g2(OUT_DIM / 64, (N_NODES + 63) / 64);
  gemm_f32<true><<<g2, 256, 0, stream>>>(Z, W1, T1, N_NODES, OUT_DIM, HIDDEN);

  // out = A @ T1
  hipMemsetAsync(out, 0, (size_t)N_NODES * OUT_DIM * sizeof(float), stream);
  int nb2 = (nE * (OUT_DIM / 4) + 255) / 256;
  scatter_add<OUT_DIM><<<nb2, 256, 0, stream>>>(T1, esrc, edst, evalv, out, nE);
}

// Round 2
// 256.266 us; speedup vs baseline: 6.6989x; 6.6989x over previous
//
#include <hip/hip_runtime.h>

#define N_NODES 10000
#define IN_DIM 256
#define HIDDEN 256
#define OUT_DIM 128

// ---------------- GEMM: C[M,N] = op(A)[M,K] @ B[K,N]; op=relu if RELU_A ----------------
template<bool RELU_A>
__global__ __launch_bounds__(256)
void gemm_f32(const float* __restrict__ A, const float* __restrict__ B,
              float* __restrict__ C, int M, int N, int K) {
  constexpr int BM = 64, BN = 64, BK = 16;
  __shared__ float As[BM][BK + 1];
  __shared__ float Bs[BK][BN];
  const int tx = threadIdx.x & 15;
  const int ty = threadIdx.x >> 4;
  const int row0 = blockIdx.y * BM;
  const int col0 = blockIdx.x * BN;
  const int t = threadIdx.x;
  const int lm = t >> 2;
  const int lk = (t & 3) * 4;
  const int bk = t >> 4;
  const int bn = (t & 15) * 4;
  float acc[4][4] = {};
  for (int k0 = 0; k0 < K; k0 += BK) {
    int ar = row0 + lm;
    float4 av = make_float4(0.f, 0.f, 0.f, 0.f);
    if (ar < M) av = *reinterpret_cast<const float4*>(A + (size_t)ar * K + k0 + lk);
    if (RELU_A) {
      av.x = fmaxf(av.x, 0.f); av.y = fmaxf(av.y, 0.f);
      av.z = fmaxf(av.z, 0.f); av.w = fmaxf(av.w, 0.f);
    }
    As[lm][lk + 0] = av.x; As[lm][lk + 1] = av.y;
    As[lm][lk + 2] = av.z; As[lm][lk + 3] = av.w;
    float4 bv = *reinterpret_cast<const float4*>(B + (size_t)(k0 + bk) * N + col0 + bn);
    *reinterpret_cast<float4*>(&Bs[bk][bn]) = bv;
    __syncthreads();
#pragma unroll
    for (int kk = 0; kk < BK; ++kk) {
      float a[4], b[4];
#pragma unroll
      for (int i = 0; i < 4; ++i) a[i] = As[ty * 4 + i][kk];
#pragma unroll
      for (int j = 0; j < 4; ++j) b[j] = Bs[kk][tx * 4 + j];
#pragma unroll
      for (int i = 0; i < 4; ++i)
#pragma unroll
        for (int j = 0; j < 4; ++j)
          acc[i][j] = fmaf(a[i], b[j], acc[i][j]);
    }
    __syncthreads();
  }
#pragma unroll
  for (int i = 0; i < 4; ++i) {
    int r = row0 + ty * 4 + i;
    if (r < M) {
#pragma unroll
      for (int j = 0; j < 4; ++j)
        C[(size_t)r * N + col0 + tx * 4 + j] = acc[i][j];
    }
  }
}

// ---------------- CSR build (by dst) ----------------
__global__ __launch_bounds__(256)
void hist_kernel(const int* __restrict__ dst, int* __restrict__ cnt, int nE) {
  int i = blockIdx.x * 256 + threadIdx.x;
  if (i < nE) atomicAdd(&cnt[dst[i]], 1);
}

// single block: exclusive scan of cnt[0..N_NODES) -> rowptr, rowcur
__global__ __launch_bounds__(256)
void scan_kernel(const int* __restrict__ cnt, int* __restrict__ rowptr,
                 int* __restrict__ rowcur) {
  __shared__ int partial[256];
  const int t = threadIdx.x;
  constexpr int PER = (N_NODES + 255) / 256;  // 40
  const int base = t * PER;
  int sum = 0;
  for (int i = 0; i < PER; ++i) {
    int idx = base + i;
    if (idx < N_NODES) sum += cnt[idx];
  }
  partial[t] = sum;
  __syncthreads();
  if (t == 0) {
    int run = 0;
    for (int i = 0; i < 256; ++i) { int v = partial[i]; partial[i] = run; run += v; }
    rowptr[N_NODES] = run;
  }
  __syncthreads();
  int run = partial[t];
  for (int i = 0; i < PER; ++i) {
    int idx = base + i;
    if (idx < N_NODES) {
      rowptr[idx] = run;
      rowcur[idx] = run;
      run += cnt[idx];
    }
  }
}

__global__ __launch_bounds__(256)
void bucket_kernel(const int* __restrict__ src, const int* __restrict__ dst,
                   const float* __restrict__ val, int* __restrict__ rowcur,
                   int* __restrict__ ssorted, float* __restrict__ vsorted, int nE) {
  int i = blockIdx.x * 256 + threadIdx.x;
  if (i < nE) {
    int d = dst[i];
    int p = atomicAdd(&rowcur[d], 1);
    ssorted[p] = src[i];
    vsorted[p] = val[i];
  }
}

// ---------------- SpMM gather: Z[n,:] = sum_{e in row n} val[e] * X[src[e],:] ----------------
// One wave (64 lanes) per node; lane owns D/64 consecutive floats.
template<int D>
__global__ __launch_bounds__(256)
void spmm_gather(const float* __restrict__ X, const int* __restrict__ ssorted,
                 const float* __restrict__ vsorted, const int* __restrict__ rowptr,
                 float* __restrict__ Z) {
  constexpr int VPT = D / 64;  // 4 (D=256) or 2 (D=128)
  const int node = blockIdx.x * 4 + (threadIdx.x >> 6);
  const int lane = threadIdx.x & 63;
  if (node >= N_NODES) return;
  const int r0 = rowptr[node];
  const int r1 = rowptr[node + 1];
  float acc[VPT] = {};
  int e = r0;
  // 2-wide unroll for ILP
  for (; e + 1 < r1; e += 2) {
    int s0 = ssorted[e], s1 = ssorted[e + 1];
    float v0 = vsorted[e], v1 = vsorted[e + 1];
    const float* x0 = X + (size_t)s0 * D + lane * VPT;
    const float* x1 = X + (size_t)s1 * D + lane * VPT;
    if (VPT == 4) {
      float4 a = *reinterpret_cast<const float4*>(x0);
      float4 b = *reinterpret_cast<const float4*>(x1);
      acc[0] = fmaf(v0, a.x, acc[0]); acc[1] = fmaf(v0, a.y, acc[1]);
      acc[2] = fmaf(v0, a.z, acc[2]); acc[3] = fmaf(v0, a.w, acc[3]);
      acc[0] = fmaf(v1, b.x, acc[0]); acc[1] = fmaf(v1, b.y, acc[1]);
      acc[2] = fmaf(v1, b.z, acc[2]); acc[3] = fmaf(v1, b.w, acc[3]);
    } else {
      float2 a = *reinterpret_cast<const float2*>(x0);
      float2 b = *reinterpret_cast<const float2*>(x1);
      acc[0] = fmaf(v0, a.x, acc[0]); acc[1] = fmaf(v0, a.y, acc[1]);
      acc[0] = fmaf(v1, b.x, acc[0]); acc[1] = fmaf(v1, b.y, acc[1]);
    }
  }
  if (e < r1) {
    int s0 = ssorted[e];
    float v0 = vsorted[e];
    const float* x0 = X + (size_t)s0 * D + lane * VPT;
    if (VPT == 4) {
      float4 a = *reinterpret_cast<const float4*>(x0);
      acc[0] = fmaf(v0, a.x, acc[0]); acc[1] = fmaf(v0, a.y, acc[1]);
      acc[2] = fmaf(v0, a.z, acc[2]); acc[3] = fmaf(v0, a.w, acc[3]);
    } else {
      float2 a = *reinterpret_cast<const float2*>(x0);
      acc[0] = fmaf(v0, a.x, acc[0]); acc[1] = fmaf(v0, a.y, acc[1]);
    }
  }
  float* zp = Z + (size_t)node * D + lane * VPT;
  if (VPT == 4) {
    float4 o; o.x = acc[0]; o.y = acc[1]; o.z = acc[2]; o.w = acc[3];
    *reinterpret_cast<float4*>(zp) = o;
  } else {
    float2 o; o.x = acc[0]; o.y = acc[1];
    *reinterpret_cast<float2*>(zp) = o;
  }
}

extern "C" void kernel_launch(void* const* d_in, const int* in_sizes, int n_in,
                              void* d_out, int out_size, void* d_ws, size_t ws_size,
                              hipStream_t stream) {
  const float* features = (const float*)d_in[0];
  const int*   esrc     = (const int*)d_in[1];
  const int*   edst     = (const int*)d_in[2];
  const float* evalv    = (const float*)d_in[3];
  const float* W0       = (const float*)d_in[4];
  const float* W1       = (const float*)d_in[5];
  const int nE = in_sizes[1];
  float* out = (float*)d_out;

  // workspace layout
  float* T0 = (float*)d_ws;                               // [N, HIDDEN]
  float* Z  = T0 + (size_t)N_NODES * HIDDEN;              // [N, HIDDEN]
  float* T1 = Z  + (size_t)N_NODES * HIDDEN;              // [N, OUT_DIM]
  float* vsorted = T1 + (size_t)N_NODES * OUT_DIM;        // [E]
  int* ssorted = (int*)(vsorted + nE);                    // [E]
  int* cnt     = ssorted + nE;                            // [N]
  int* rowptr  = cnt + N_NODES;                           // [N+1]
  int* rowcur  = rowptr + N_NODES + 1;                    // [N]

  const int ebk = (nE + 255) / 256;

  // ---- build CSR by dst (same graph both layers) ----
  hipMemsetAsync(cnt, 0, N_NODES * sizeof(int), stream);
  hist_kernel<<<ebk, 256, 0, stream>>>(edst, cnt, nE);
  scan_kernel<<<1, 256, 0, stream>>>(cnt, rowptr, rowcur);
  bucket_kernel<<<ebk, 256, 0, stream>>>(esrc, edst, evalv, rowcur, ssorted, vsorted, nE);

  // ---- T0 = F @ W0 ----
  dim3 g1(HIDDEN / 64, (N_NODES + 63) / 64);
  gemm_f32<false><<<g1, 256, 0, stream>>>(features, W0, T0, N_NODES, HIDDEN, IN_DIM);

  // ---- Z = A @ T0 (gather) ----
  spmm_gather<HIDDEN><<<(N_NODES + 3) / 4, 256, 0, stream>>>(T0, ssorted, vsorted, rowptr, Z);

  // ---- T1 = relu(Z) @ W1 ----
  dim3 g2(OUT_DIM / 64, (N_NODES + 63) / 64);
  gemm_f32<true><<<g2, 256, 0, stream>>>(Z, W1, T1, N_NODES, OUT_DIM, HIDDEN);

  // ---- out = A @ T1 (gather) ----
  spmm_gather<OUT_DIM><<<(N_NODES + 3) / 4, 256, 0, stream>>>(T1, ssorted, vsorted, rowptr, out);
}

// Round 3
// 218.862 us; speedup vs baseline: 7.8437x; 1.1709x over previous
//
#include <hip/hip_runtime.h>

#define N_NODES 10000
#define IN_DIM 256
#define HIDDEN 256
#define OUT_DIM 128

typedef __attribute__((ext_vector_type(8))) short bf16x8;
typedef __attribute__((ext_vector_type(4))) float f32x4;
typedef __attribute__((ext_vector_type(4))) unsigned short u16x4;
typedef __attribute__((ext_vector_type(2))) unsigned short u16x2;

__device__ __forceinline__ unsigned short f2bf(float x) {
  union { float f; unsigned u; } c; c.f = x;
  unsigned r = (c.u + 0x7FFFu + ((c.u >> 16) & 1u)) >> 16;
  return (unsigned short)r;
}
__device__ __forceinline__ float bf2f(unsigned short u) {
  union { unsigned u; float f; } c; c.u = ((unsigned)u) << 16;
  return c.f;
}

// ---- fused f32->bf16 conversion: F (plain), W0 (transposed), W1 (transposed) ----
__global__ __launch_bounds__(256)
void convert_kernel(const float* __restrict__ F, const float* __restrict__ W0,
                    const float* __restrict__ W1, unsigned short* __restrict__ Fb,
                    unsigned short* __restrict__ W0t, unsigned short* __restrict__ W1t) {
  const int nF8 = N_NODES * IN_DIM / 8;        // 320000 chunks of 8
  const int nW0 = IN_DIM * HIDDEN;             // 65536
  const int nW1 = HIDDEN * OUT_DIM;            // 32768
  int gid = blockIdx.x * 256 + threadIdx.x;
  if (gid < nF8) {
    float4 a = reinterpret_cast<const float4*>(F)[gid * 2];
    float4 b = reinterpret_cast<const float4*>(F)[gid * 2 + 1];
    u16x4 lo, hi;
    lo[0] = f2bf(a.x); lo[1] = f2bf(a.y); lo[2] = f2bf(a.z); lo[3] = f2bf(a.w);
    hi[0] = f2bf(b.x); hi[1] = f2bf(b.y); hi[2] = f2bf(b.z); hi[3] = f2bf(b.w);
    reinterpret_cast<u16x4*>(Fb)[gid * 2] = lo;
    reinterpret_cast<u16x4*>(Fb)[gid * 2 + 1] = hi;
  } else if (gid < nF8 + nW0) {
    int i = gid - nF8;
    int k = i >> 8, n = i & 255;               // W0 is [256][256]
    W0t[n * 256 + k] = f2bf(W0[k * 256 + n]);
  } else if (gid < nF8 + nW0 + nW1) {
    int i = gid - nF8 - nW0;
    int k = i >> 7, n = i & 127;               // W1 is [256][128]
    W1t[n * 256 + k] = f2bf(W1[k * 128 + n]);
  }
}

// ---- CSR build (by dst) ----
__global__ __launch_bounds__(256)
void hist_kernel(const int* __restrict__ dst, int* __restrict__ cnt, int nE) {
  int i = blockIdx.x * 256 + threadIdx.x;
  if (i < nE) atomicAdd(&cnt[dst[i]], 1);
}

__global__ __launch_bounds__(256)
void scan_kernel(const int* __restrict__ cnt, int* __restrict__ rowptr,
                 int* __restrict__ rowcur) {
  const int t = threadIdx.x;
  constexpr int PER = (N_NODES + 255) / 256;   // 40
  const int base = t * PER;
  int sum = 0;
  for (int i = 0; i < PER; ++i) {
    int idx = base + i;
    if (idx < N_NODES) sum += cnt[idx];
  }
  // wave-level inclusive scan of per-thread sums
  const int lane = t & 63, wv = t >> 6;
  int x = sum;
  for (int off = 1; off < 64; off <<= 1) {
    int y = __shfl_up(x, off);
    if (lane >= off) x += y;
  }
  __shared__ int wsum[4];
  if (lane == 63) wsum[wv] = x;
  __syncthreads();
  int wo = 0;
  for (int i = 0; i < wv; ++i) wo += wsum[i];
  if (t == 255) rowptr[N_NODES] = wo + x;
  int run = wo + x - sum;                      // exclusive prefix at this thread's chunk
  for (int i = 0; i < PER; ++i) {
    int idx = base + i;
    if (idx < N_NODES) {
      rowptr[idx] = run;
      rowcur[idx] = run;
      run += cnt[idx];
    }
  }
}

__global__ __launch_bounds__(256)
void bucket_kernel(const int* __restrict__ src, const int* __restrict__ dst,
                   const float* __restrict__ val, int* __restrict__ rowcur,
                   int* __restrict__ ssorted, float* __restrict__ vsorted, int nE) {
  int i = blockIdx.x * 256 + threadIdx.x;
  if (i < nE) {
    int d = dst[i];
    int p = atomicAdd(&rowcur[d], 1);
    ssorted[p] = src[i];
    vsorted[p] = val[i];
  }
}

// ---- MFMA GEMM: C[M,NDIM] = op(A)[M,256] @ Bt[NDIM,256]^T, all bf16, f32 accum ----
// 4 waves/block; wave w does rows r0..r0+15 x 64 cols. No LDS (B is L2-resident).
template<int NDIM, bool RELU>
__global__ __launch_bounds__(256)
void gemm_mfma(const unsigned short* __restrict__ A, const unsigned short* __restrict__ Bt,
               unsigned short* __restrict__ C, int M) {
  const int w = threadIdx.x >> 6;
  const int l = threadIdx.x & 63;
  const int r0 = blockIdx.y * 64 + w * 16;
  const int c0 = blockIdx.x * 64;
  const int arow = r0 + (l & 15);
  const int kof = (l >> 4) * 8;
  const bool rv = arow < M;
  const unsigned short* Ap = A + (size_t)arow * 256 + kof;
  f32x4 acc[4] = {};
#pragma unroll
  for (int k0 = 0; k0 < 256; k0 += 32) {
    bf16x8 af = {};
    if (rv) af = *reinterpret_cast<const bf16x8*>(Ap + k0);
    if (RELU) {
#pragma unroll
      for (int i = 0; i < 8; ++i) af[i] = (af[i] < 0) ? (short)0 : af[i];
    }
#pragma unroll
    for (int j = 0; j < 4; ++j) {
      bf16x8 bfr = *reinterpret_cast<const bf16x8*>(
          Bt + (size_t)(c0 + j * 16 + (l & 15)) * 256 + k0 + kof);
      acc[j] = __builtin_amdgcn_mfma_f32_16x16x32_bf16(af, bfr, acc[j], 0, 0, 0);
    }
  }
  const int orow0 = r0 + ((l >> 4) << 2);      // C/D: col=lane&15, row=(lane>>4)*4+reg
#pragma unroll
  for (int j = 0; j < 4; ++j) {
    const int col = c0 + j * 16 + (l & 15);
#pragma unroll
    for (int r = 0; r < 4; ++r) {
      int orow = orow0 + r;
      if (orow < M) C[(size_t)orow * NDIM + col] = f2bf(acc[j][r]);
    }
  }
}

// ---- SpMM gather on bf16 rows: Z[n,:] = sum val[e] * X[src[e],:] ----
template<int D, bool OUTBF>
__global__ __launch_bounds__(256)
void spmm_gather(const unsigned short* __restrict__ X, const int* __restrict__ ss,
                 const float* __restrict__ vs, const int* __restrict__ rp,
                 void* __restrict__ Zout) {
  constexpr int VPT = D / 64;                  // 4 (D=256) or 2 (D=128)
  const int node = blockIdx.x * 4 + (threadIdx.x >> 6);
  const int lane = threadIdx.x & 63;
  const int r0 = rp[node];
  const int r1 = rp[node + 1];
  float acc[VPT] = {};
  const unsigned short* Xl = X + lane * VPT;
  int e = r0;
  for (; e + 1 < r1; e += 2) {
    int s0 = ss[e], s1 = ss[e + 1];
    float v0 = vs[e], v1 = vs[e + 1];
    if (VPT == 4) {
      u16x4 a = *reinterpret_cast<const u16x4*>(Xl + (size_t)s0 * D);
      u16x4 b = *reinterpret_cast<const u16x4*>(Xl + (size_t)s1 * D);
#pragma unroll
      for (int i = 0; i < 4; ++i) acc[i] = fmaf(v0, bf2f(a[i]), acc[i]);
#pragma unroll
      for (int i = 0; i < 4; ++i) acc[i] = fmaf(v1, bf2f(b[i]), acc[i]);
    } else {
      u16x2 a = *reinterpret_cast<const u16x2*>(Xl + (size_t)s0 * D);
      u16x2 b = *reinterpret_cast<const u16x2*>(Xl + (size_t)s1 * D);
      acc[0] = fmaf(v0, bf2f(a[0]), acc[0]); acc[1] = fmaf(v0, bf2f(a[1]), acc[1]);
      acc[0] = fmaf(v1, bf2f(b[0]), acc[0]); acc[1] = fmaf(v1, bf2f(b[1]), acc[1]);
    }
  }
  if (e < r1) {
    int s0 = ss[e];
    float v0 = vs[e];
    if (VPT == 4) {
      u16x4 a = *reinterpret_cast<const u16x4*>(Xl + (size_t)s0 * D);
#pragma unroll
      for (int i = 0; i < 4; ++i) acc[i] = fmaf(v0, bf2f(a[i]), acc[i]);
    } else {
      u16x2 a = *reinterpret_cast<const u16x2*>(Xl + (size_t)s0 * D);
      acc[0] = fmaf(v0, bf2f(a[0]), acc[0]); acc[1] = fmaf(v0, bf2f(a[1]), acc[1]);
    }
  }
  if (OUTBF) {
    unsigned short* Z = (unsigned short*)Zout + (size_t)node * D + lane * VPT;
    if (VPT == 4) {
      u16x4 o; o[0] = f2bf(acc[0]); o[1] = f2bf(acc[1]); o[2] = f2bf(acc[2]); o[3] = f2bf(acc[3]);
      *reinterpret_cast<u16x4*>(Z) = o;
    } else {
      u16x2 o; o[0] = f2bf(acc[0]); o[1] = f2bf(acc[1]);
      *reinterpret_cast<u16x2*>(Z) = o;
    }
  } else {
    float* Z = (float*)Zout + (size_t)node * D + lane * VPT;
    if (VPT == 4) {
      float4 o; o.x = acc[0]; o.y = acc[1]; o.z = acc[2]; o.w = acc[3];
      *reinterpret_cast<float4*>(Z) = o;
    } else {
      float2 o; o.x = acc[0]; o.y = acc[1];
      *reinterpret_cast<float2*>(Z) = o;
    }
  }
}

extern "C" void kernel_launch(void* const* d_in, const int* in_sizes, int n_in,
                              void* d_out, int out_size, void* d_ws, size_t ws_size,
                              hipStream_t stream) {
  const float* features = (const float*)d_in[0];
  const int*   esrc     = (const int*)d_in[1];
  const int*   edst     = (const int*)d_in[2];
  const float* evalv    = (const float*)d_in[3];
  const float* W0       = (const float*)d_in[4];
  const float* W1       = (const float*)d_in[5];
  const int nE = in_sizes[1];
  float* out = (float*)d_out;

  // workspace (all 16B aligned: every chunk size is a multiple of 16B)
  unsigned short* Fb  = (unsigned short*)d_ws;                 // [N,256] bf16
  unsigned short* W0t = Fb  + (size_t)N_NODES * IN_DIM;        // [256,256] (transposed)
  unsigned short* W1t = W0t + (size_t)IN_DIM * HIDDEN;         // [128,256] (transposed)
  unsigned short* T0b = W1t + (size_t)OUT_DIM * HIDDEN;        // [N,256] bf16
  unsigned short* Zb  = T0b + (size_t)N_NODES * HIDDEN;        // [N,256] bf16
  unsigned short* T1b = Zb  + (size_t)N_NODES * HIDDEN;        // [N,128] bf16
  float* vsorted = (float*)(T1b + (size_t)N_NODES * OUT_DIM);  // [E]
  int* ssorted = (int*)(vsorted + nE);                         // [E]
  int* cnt     = ssorted + nE;                                 // [N]
  int* rowptr  = cnt + N_NODES;                                // [N+1]
  int* rowcur  = rowptr + N_NODES + 1;                         // [N]

  const int ebk = (nE + 255) / 256;
  const int ncvt = (N_NODES * IN_DIM / 8 + IN_DIM * HIDDEN + HIDDEN * OUT_DIM + 255) / 256;

  // conversions + CSR build
  convert_kernel<<<ncvt, 256, 0, stream>>>(features, W0, W1, Fb, W0t, W1t);
  hipMemsetAsync(cnt, 0, N_NODES * sizeof(int), stream);
  hist_kernel<<<ebk, 256, 0, stream>>>(edst, cnt, nE);
  scan_kernel<<<1, 256, 0, stream>>>(cnt, rowptr, rowcur);
  bucket_kernel<<<ebk, 256, 0, stream>>>(esrc, edst, evalv, rowcur, ssorted, vsorted, nE);

  // T0 = F @ W0
  gemm_mfma<HIDDEN, false><<<dim3(HIDDEN / 64, (N_NODES + 63) / 64), 256, 0, stream>>>(
      Fb, W0t, T0b, N_NODES);
  // Z = A @ T0
  spmm_gather<HIDDEN, true><<<(N_NODES + 3) / 4, 256, 0, stream>>>(
      T0b, ssorted, vsorted, rowptr, Zb);
  // T1 = relu(Z) @ W1
  gemm_mfma<OUT_DIM, true><<<dim3(OUT_DIM / 64, (N_NODES + 63) / 64), 256, 0, stream>>>(
      Zb, W1t, T1b, N_NODES);
  // out = A @ T1
  spmm_gather<OUT_DIM, false><<<(N_NODES + 3) / 4, 256, 0, stream>>>(
      T1b, ssorted, vsorted, rowptr, out);
}

// Round 4
// 209.503 us; speedup vs baseline: 8.1941x; 1.0447x over previous
//
#include <hip/hip_runtime.h>

#define N_NODES 10000
#define IN_DIM 256
#define HIDDEN 256
#define OUT_DIM 128

typedef __attribute__((ext_vector_type(8))) short bf16x8;
typedef __attribute__((ext_vector_type(4))) float f32x4;
typedef __attribute__((ext_vector_type(4))) unsigned short u16x4;

__device__ __forceinline__ unsigned short f2bf(float x) {
  union { float f; unsigned u; } c; c.f = x;
  unsigned r = (c.u + 0x7FFFu + ((c.u >> 16) & 1u)) >> 16;
  return (unsigned short)r;
}
__device__ __forceinline__ float bf2f(unsigned short u) {
  union { unsigned u; float f; } c; c.u = ((unsigned)u) << 16;
  return c.f;
}

// ---- fused: F->bf16, W0^T->bf16, W1^T->bf16, zero cnt ----
__global__ __launch_bounds__(256)
void convert_kernel(const float* __restrict__ F, const float* __restrict__ W0,
                    const float* __restrict__ W1, unsigned short* __restrict__ Fb,
                    unsigned short* __restrict__ W0t, unsigned short* __restrict__ W1t,
                    int* __restrict__ cnt) {
  const int nF8 = N_NODES * IN_DIM / 8;        // 320000
  const int nW0 = IN_DIM * HIDDEN;             // 65536
  const int nW1 = HIDDEN * OUT_DIM;            // 32768
  int gid = blockIdx.x * 256 + threadIdx.x;
  if (gid < nF8) {
    float4 a = reinterpret_cast<const float4*>(F)[gid * 2];
    float4 b = reinterpret_cast<const float4*>(F)[gid * 2 + 1];
    u16x4 lo, hi;
    lo[0] = f2bf(a.x); lo[1] = f2bf(a.y); lo[2] = f2bf(a.z); lo[3] = f2bf(a.w);
    hi[0] = f2bf(b.x); hi[1] = f2bf(b.y); hi[2] = f2bf(b.z); hi[3] = f2bf(b.w);
    reinterpret_cast<u16x4*>(Fb)[gid * 2] = lo;
    reinterpret_cast<u16x4*>(Fb)[gid * 2 + 1] = hi;
  } else if (gid < nF8 + nW0) {
    int i = gid - nF8;
    int k = i >> 8, n = i & 255;               // W0 [256][256]
    W0t[n * 256 + k] = f2bf(W0[k * 256 + n]);
  } else if (gid < nF8 + nW0 + nW1) {
    int i = gid - nF8 - nW0;
    int k = i >> 7, n = i & 127;               // W1 [256][128]
    W1t[n * 256 + k] = f2bf(W1[k * 128 + n]);
  } else if (gid < nF8 + nW0 + nW1 + N_NODES) {
    cnt[gid - nF8 - nW0 - nW1] = 0;
  }
}

// ---- CSR build (by dst) ----
__global__ __launch_bounds__(256)
void hist_kernel(const int* __restrict__ dst, int* __restrict__ cnt, int nE) {
  int i = blockIdx.x * 256 + threadIdx.x;
  if (i < nE) atomicAdd(&cnt[dst[i]], 1);
}

__global__ __launch_bounds__(256)
void scan_kernel(const int* __restrict__ cnt, int* __restrict__ rowptr,
                 int* __restrict__ rowcur) {
  const int t = threadIdx.x;
  constexpr int PER = (N_NODES + 255) / 256;   // 40
  const int base = t * PER;
  int sum = 0;
  for (int i = 0; i < PER; ++i) {
    int idx = base + i;
    if (idx < N_NODES) sum += cnt[idx];
  }
  const int lane = t & 63, wv = t >> 6;
  int x = sum;
  for (int off = 1; off < 64; off <<= 1) {
    int y = __shfl_up(x, off);
    if (lane >= off) x += y;
  }
  __shared__ int wsum[4];
  if (lane == 63) wsum[wv] = x;
  __syncthreads();
  int wo = 0;
  for (int i = 0; i < wv; ++i) wo += wsum[i];
  if (t == 255) rowptr[N_NODES] = wo + x;
  int run = wo + x - sum;
  for (int i = 0; i < PER; ++i) {
    int idx = base + i;
    if (idx < N_NODES) {
      rowptr[idx] = run;
      rowcur[idx] = run;
      run += cnt[idx];
    }
  }
}

// packed (src, val) -> single 8B store
__global__ __launch_bounds__(256)
void bucket_kernel(const int* __restrict__ src, const int* __restrict__ dst,
                   const float* __restrict__ val, int* __restrict__ rowcur,
                   int2* __restrict__ edges, int nE) {
  int i = blockIdx.x * 256 + threadIdx.x;
  if (i < nE) {
    int d = dst[i];
    int p = atomicAdd(&rowcur[d], 1);
    edges[p] = make_int2(src[i], __float_as_int(val[i]));
  }
}

// ---- layer-1 GEMM: T0[M,256] = F[M,256] @ W0t[256,256]^T (bf16, f32 accum) ----
__global__ __launch_bounds__(256)
void gemm_mfma(const unsigned short* __restrict__ A, const unsigned short* __restrict__ Bt,
               unsigned short* __restrict__ C, int M) {
  const int w = threadIdx.x >> 6;
  const int l = threadIdx.x & 63;
  const int r0 = blockIdx.y * 64 + w * 16;
  const int c0 = blockIdx.x * 64;
  const int arow = r0 + (l & 15);
  const int kof = (l >> 4) * 8;
  const bool rv = arow < M;
  const unsigned short* Ap = A + (size_t)arow * 256 + kof;
  f32x4 acc[4] = {};
#pragma unroll
  for (int k0 = 0; k0 < 256; k0 += 32) {
    bf16x8 af = {};
    if (rv) af = *reinterpret_cast<const bf16x8*>(Ap + k0);
#pragma unroll
    for (int j = 0; j < 4; ++j) {
      bf16x8 bfr = *reinterpret_cast<const bf16x8*>(
          Bt + (size_t)(c0 + j * 16 + (l & 15)) * 256 + k0 + kof);
      acc[j] = __builtin_amdgcn_mfma_f32_16x16x32_bf16(af, bfr, acc[j], 0, 0, 0);
    }
  }
  const int orow0 = r0 + ((l >> 4) << 2);
#pragma unroll
  for (int j = 0; j < 4; ++j) {
    const int col = c0 + j * 16 + (l & 15);
#pragma unroll
    for (int r = 0; r < 4; ++r) {
      int orow = orow0 + r;
      if (orow < HIDDEN * 0 + 2147483647 && orow < N_NODES) // M==N_NODES here
        C[(size_t)orow * HIDDEN + col] = f2bf(acc[j][r]);
    }
  }
}

// ---- fused: Z-rows = spmm(T0b) (16 nodes/block) -> LDS -> relu -> @ W1t -> T1b ----
__global__ __launch_bounds__(256)
void fused_spmm_gemm(const unsigned short* __restrict__ T0b,
                     const int2* __restrict__ edges,
                     const int* __restrict__ rp,
                     const unsigned short* __restrict__ W1t,
                     unsigned short* __restrict__ T1b) {
  __shared__ unsigned short Zs[16 * 256];      // 8KB, XOR-swizzled
  const int wv = threadIdx.x >> 6;
  const int l  = threadIdx.x & 63;
  const int nb = blockIdx.x * 16;
  // phase 1: each wave gathers 4 node rows (D=256, lane owns 4 cols)
  const unsigned short* Xl = T0b + l * 4;
  for (int i = 0; i < 4; ++i) {
    const int r = wv * 4 + i;
    const int node = nb + r;
    const int r0 = rp[node], r1 = rp[node + 1];
    float acc[4] = {};
    int e = r0;
    for (; e + 3 < r1; e += 4) {
      int2 ea = edges[e], eb = edges[e + 1], ec = edges[e + 2], ed = edges[e + 3];
      u16x4 a = *reinterpret_cast<const u16x4*>(Xl + (size_t)ea.x * 256);
      u16x4 b = *reinterpret_cast<const u16x4*>(Xl + (size_t)eb.x * 256);
      u16x4 c = *reinterpret_cast<const u16x4*>(Xl + (size_t)ec.x * 256);
      u16x4 d = *reinterpret_cast<const u16x4*>(Xl + (size_t)ed.x * 256);
      float va = __int_as_float(ea.y), vb = __int_as_float(eb.y);
      float vc = __int_as_float(ec.y), vd = __int_as_float(ed.y);
#pragma unroll
      for (int q = 0; q < 4; ++q) acc[q] = fmaf(va, bf2f(a[q]), acc[q]);
#pragma unroll
      for (int q = 0; q < 4; ++q) acc[q] = fmaf(vb, bf2f(b[q]), acc[q]);
#pragma unroll
      for (int q = 0; q < 4; ++q) acc[q] = fmaf(vc, bf2f(c[q]), acc[q]);
#pragma unroll
      for (int q = 0; q < 4; ++q) acc[q] = fmaf(vd, bf2f(d[q]), acc[q]);
    }
    for (; e < r1; ++e) {
      int2 ea = edges[e];
      u16x4 a = *reinterpret_cast<const u16x4*>(Xl + (size_t)ea.x * 256);
      float va = __int_as_float(ea.y);
#pragma unroll
      for (int q = 0; q < 4; ++q) acc[q] = fmaf(va, bf2f(a[q]), acc[q]);
    }
    // relu + bf16, swizzled 8B LDS write: logical byte = r*512 + l*8
    u16x4 o;
#pragma unroll
    for (int q = 0; q < 4; ++q) o[q] = f2bf(fmaxf(acc[q], 0.f));
    int off = (r * 512 + l * 8) ^ ((r & 7) << 4);
    *reinterpret_cast<u16x4*>(reinterpret_cast<char*>(Zs) + off) = o;
  }
  __syncthreads();
  // phase 2: 16x256 (LDS) @ W1t[128,256]^T -> 16x128; wave wv covers 32 cols
  const int row = l & 15;
  const int kof = (l >> 4) * 8;
  const int c0 = wv * 32;
  f32x4 acc2[2] = {};
#pragma unroll
  for (int k0 = 0; k0 < 256; k0 += 32) {
    int aoff = (row * 512 + (k0 + kof) * 2) ^ ((row & 7) << 4);
    bf16x8 af = *reinterpret_cast<const bf16x8*>(reinterpret_cast<const char*>(Zs) + aoff);
#pragma unroll
    for (int j = 0; j < 2; ++j) {
      bf16x8 bfr = *reinterpret_cast<const bf16x8*>(
          W1t + (size_t)(c0 + j * 16 + row) * 256 + k0 + kof);
      acc2[j] = __builtin_amdgcn_mfma_f32_16x16x32_bf16(af, bfr, acc2[j], 0, 0, 0);
    }
  }
  const int orow0 = (l >> 4) * 4;
#pragma unroll
  for (int j = 0; j < 2; ++j) {
    const int col = c0 + j * 16 + row;
#pragma unroll
    for (int rr = 0; rr < 4; ++rr) {
      const int node = nb + orow0 + rr;
      T1b[(size_t)node * OUT_DIM + col] = f2bf(acc2[j][rr]);
    }
  }
}

// ---- final spmm: out[n,:128] = sum val * T1b[src,:]; 2 nodes per wave ----
__global__ __launch_bounds__(256)
void spmm_out(const unsigned short* __restrict__ T1b,
              const int2* __restrict__ edges,
              const int* __restrict__ rp,
              float* __restrict__ out) {
  const int wv = threadIdx.x >> 6;
  const int lane = threadIdx.x & 63;
  const int half = lane >> 5;
  const int hl = lane & 31;                    // 32 lanes x 4 cols = 128
  const int node = blockIdx.x * 8 + wv * 2 + half;
  const int r0 = rp[node], r1 = rp[node + 1];
  float acc[4] = {};
  const unsigned short* Xl = T1b + hl * 4;
  int e = r0;
  for (; e + 3 < r1; e += 4) {
    int2 ea = edges[e], eb = edges[e + 1], ec = edges[e + 2], ed = edges[e + 3];
    u16x4 a = *reinterpret_cast<const u16x4*>(Xl + (size_t)ea.x * 128);
    u16x4 b = *reinterpret_cast<const u16x4*>(Xl + (size_t)eb.x * 128);
    u16x4 c = *reinterpret_cast<const u16x4*>(Xl + (size_t)ec.x * 128);
    u16x4 d = *reinterpret_cast<const u16x4*>(Xl + (size_t)ed.x * 128);
    float va = __int_as_float(ea.y), vb = __int_as_float(eb.y);
    float vc = __int_as_float(ec.y), vd = __int_as_float(ed.y);
#pragma unroll
    for (int q = 0; q < 4; ++q) acc[q] = fmaf(va, bf2f(a[q]), acc[q]);
#pragma unroll
    for (int q = 0; q < 4; ++q) acc[q] = fmaf(vb, bf2f(b[q]), acc[q]);
#pragma unroll
    for (int q = 0; q < 4; ++q) acc[q] = fmaf(vc, bf2f(c[q]), acc[q]);
#pragma unroll
    for (int q = 0; q < 4; ++q) acc[q] = fmaf(vd, bf2f(d[q]), acc[q]);
  }
  for (; e < r1; ++e) {
    int2 ea = edges[e];
    u16x4 a = *reinterpret_cast<const u16x4*>(Xl + (size_t)ea.x * 128);
    float va = __int_as_float(ea.y);
#pragma unroll
    for (int q = 0; q < 4; ++q) acc[q] = fmaf(va, bf2f(a[q]), acc[q]);
  }
  float4 o; o.x = acc[0]; o.y = acc[1]; o.z = acc[2]; o.w = acc[3];
  *reinterpret_cast<float4*>(out + (size_t)node * OUT_DIM + hl * 4) = o;
}

extern "C" void kernel_launch(void* const* d_in, const int* in_sizes, int n_in,
                              void* d_out, int out_size, void* d_ws, size_t ws_size,
                              hipStream_t stream) {
  const float* features = (const float*)d_in[0];
  const int*   esrc     = (const int*)d_in[1];
  const int*   edst     = (const int*)d_in[2];
  const float* evalv    = (const float*)d_in[3];
  const float* W0       = (const float*)d_in[4];
  const float* W1       = (const float*)d_in[5];
  const int nE = in_sizes[1];
  float* out = (float*)d_out;

  unsigned short* Fb  = (unsigned short*)d_ws;                 // [N,256]
  unsigned short* W0t = Fb  + (size_t)N_NODES * IN_DIM;        // [256,256]
  unsigned short* W1t = W0t + (size_t)IN_DIM * HIDDEN;         // [128,256]
  unsigned short* T0b = W1t + (size_t)OUT_DIM * HIDDEN;        // [N,256]
  unsigned short* T1b = T0b + (size_t)N_NODES * HIDDEN;        // [N,128]
  int2* edges  = (int2*)(T1b + (size_t)N_NODES * OUT_DIM);     // [E] (8B aligned)
  int* cnt     = (int*)(edges + nE);                           // [N]
  int* rowptr  = cnt + N_NODES;                                // [N+1]
  int* rowcur  = rowptr + N_NODES + 1;                         // [N]

  const int ebk = (nE + 255) / 256;
  const int ncvt = (N_NODES * IN_DIM / 8 + IN_DIM * HIDDEN + HIDDEN * OUT_DIM
                    + N_NODES + 255) / 256;

  convert_kernel<<<ncvt, 256, 0, stream>>>(features, W0, W1, Fb, W0t, W1t, cnt);
  hist_kernel<<<ebk, 256, 0, stream>>>(edst, cnt, nE);
  scan_kernel<<<1, 256, 0, stream>>>(cnt, rowptr, rowcur);
  bucket_kernel<<<ebk, 256, 0, stream>>>(esrc, edst, evalv, rowcur, edges, nE);

  // T0 = F @ W0
  gemm_mfma<<<dim3(HIDDEN / 64, (N_NODES + 63) / 64), 256, 0, stream>>>(Fb, W0t, T0b, N_NODES);
  // T1 = relu(A @ T0) @ W1  (fused spmm + GEMM)
  fused_spmm_gemm<<<N_NODES / 16, 256, 0, stream>>>(T0b, edges, rowptr, W1t, T1b);
  // out = A @ T1
  spmm_out<<<N_NODES / 8, 256, 0, stream>>>(T1b, edges, rowptr, out);
}

// Round 5
// 173.865 us; speedup vs baseline: 9.8737x; 1.2050x over previous
//
#include <hip/hip_runtime.h>

#define N_NODES 10000
#define IN_DIM 256
#define HIDDEN 256
#define OUT_DIM 128

typedef __attribute__((ext_vector_type(8))) short bf16x8;
typedef __attribute__((ext_vector_type(4))) float f32x4;
typedef __attribute__((ext_vector_type(4))) unsigned short u16x4;

__device__ __forceinline__ unsigned short f2bf(float x) {
  union { float f; unsigned u; } c; c.f = x;
  unsigned r = (c.u + 0x7FFFu + ((c.u >> 16) & 1u)) >> 16;
  return (unsigned short)r;
}
__device__ __forceinline__ float bf2f(unsigned short u) {
  union { unsigned u; float f; } c; c.u = ((unsigned)u) << 16;
  return c.f;
}

// ---- hist + W0^T/W1^T bf16 convert (coalesced writes); cnt pre-zeroed by memset ----
__global__ __launch_bounds__(256)
void hist_convW(const int* __restrict__ dst, int* __restrict__ cnt,
                const float* __restrict__ W0, const float* __restrict__ W1,
                unsigned short* __restrict__ W0t, unsigned short* __restrict__ W1t,
                int nE) {
  int gid = blockIdx.x * 256 + threadIdx.x;
  if (gid < nE) atomicAdd(&cnt[dst[gid]], 1);
  if (gid < IN_DIM * HIDDEN) {               // W0 [256][256] -> W0t[n][k]
    int k = gid & 255, n = gid >> 8;
    W0t[n * 256 + k] = f2bf(W0[k * 256 + n]);
  } else if (gid < IN_DIM * HIDDEN + HIDDEN * OUT_DIM) {  // W1 [256][128] -> W1t[n][k]
    int i = gid - IN_DIM * HIDDEN;
    int k = i & 255, n = i >> 8;
    W1t[n * 256 + k] = f2bf(W1[k * 128 + n]);
  }
}

// ---- single-block 1024-thread exclusive scan of cnt -> rowptr, rowcur ----
__global__ __launch_bounds__(1024)
void scan_kernel(const int* __restrict__ cnt, int* __restrict__ rowptr,
                 int* __restrict__ rowcur) {
  const int t = threadIdx.x;
  const int lane = t & 63, wv = t >> 6;       // 16 waves
  constexpr int PER = 10;
  const int base = t * PER;
  int c[PER];
  int sum = 0;
#pragma unroll
  for (int i = 0; i < PER; ++i) {
    int idx = base + i;
    c[i] = (idx < N_NODES) ? cnt[idx] : 0;
    sum += c[i];
  }
  int x = sum;                                // wave inclusive scan
  for (int off = 1; off < 64; off <<= 1) {
    int y = __shfl_up(x, off);
    if (lane >= off) x += y;
  }
  __shared__ int wsum[16], wpre[16];
  if (lane == 63) wsum[wv] = x;
  __syncthreads();
  if (t == 0) {
    int run = 0;
#pragma unroll
    for (int i = 0; i < 16; ++i) { wpre[i] = run; run += wsum[i]; }
  }
  __syncthreads();
  int run = wpre[wv] + x - sum;               // exclusive prefix
#pragma unroll
  for (int i = 0; i < PER; ++i) {
    int idx = base + i;
    if (idx < N_NODES) {
      rowptr[idx] = run;
      rowcur[idx] = run;
      run += c[i];
    }
  }
  if (t == 1023) rowptr[N_NODES] = run;
}

// ---- bucket: packed (src,val) 8B stores ----
__global__ __launch_bounds__(256)
void bucket_kernel(const int* __restrict__ src, const int* __restrict__ dst,
                   const float* __restrict__ val, int* __restrict__ rowcur,
                   int2* __restrict__ edges, int nE) {
  int i = blockIdx.x * 256 + threadIdx.x;
  if (i < nE) {
    int d = dst[i];
    int p = atomicAdd(&rowcur[d], 1);
    edges[p] = make_int2(src[i], __float_as_int(val[i]));
  }
}

// ---- layer-1 GEMM: T0b[M,256] = bf16(F)[M,256] @ W0t[256,256]^T, f32 A-loads ----
__global__ __launch_bounds__(256)
void gemm_mfma(const float* __restrict__ F, const unsigned short* __restrict__ Bt,
               unsigned short* __restrict__ C) {
  const int w = threadIdx.x >> 6;
  const int l = threadIdx.x & 63;
  const int r0 = blockIdx.y * 64 + w * 16;
  const int c0 = blockIdx.x * 64;
  const int arow = r0 + (l & 15);
  const int kof = (l >> 4) * 8;
  const bool rv = arow < N_NODES;
  const float* Ap = F + (size_t)arow * 256 + kof;
  f32x4 acc[4] = {};
#pragma unroll
  for (int k0 = 0; k0 < 256; k0 += 32) {
    bf16x8 af = {};
    if (rv) {
      float4 fa = *reinterpret_cast<const float4*>(Ap + k0);
      float4 fb = *reinterpret_cast<const float4*>(Ap + k0 + 4);
      af[0] = (short)f2bf(fa.x); af[1] = (short)f2bf(fa.y);
      af[2] = (short)f2bf(fa.z); af[3] = (short)f2bf(fa.w);
      af[4] = (short)f2bf(fb.x); af[5] = (short)f2bf(fb.y);
      af[6] = (short)f2bf(fb.z); af[7] = (short)f2bf(fb.w);
    }
#pragma unroll
    for (int j = 0; j < 4; ++j) {
      bf16x8 bfr = *reinterpret_cast<const bf16x8*>(
          Bt + (size_t)(c0 + j * 16 + (l & 15)) * 256 + k0 + kof);
      acc[j] = __builtin_amdgcn_mfma_f32_16x16x32_bf16(af, bfr, acc[j], 0, 0, 0);
    }
  }
  const int orow0 = r0 + ((l >> 4) << 2);
#pragma unroll
  for (int j = 0; j < 4; ++j) {
    const int col = c0 + j * 16 + (l & 15);
#pragma unroll
    for (int r = 0; r < 4; ++r) {
      int orow = orow0 + r;
      if (orow < N_NODES) C[(size_t)orow * HIDDEN + col] = f2bf(acc[j][r]);
    }
  }
}

// ---- fused: 16 nodes/block spmm-gather -> LDS(relu,bf16,swz) -> @W1t -> T1b ----
__global__ __launch_bounds__(512)
void fused_spmm_gemm(const unsigned short* __restrict__ T0b,
                     const int2* __restrict__ edges,
                     const int* __restrict__ rp,
                     const unsigned short* __restrict__ W1t,
                     unsigned short* __restrict__ T1b) {
  __shared__ unsigned short Zs[16 * 256];     // 8KB, XOR-swizzled
  const int wv = threadIdx.x >> 6;            // 0..7
  const int l  = threadIdx.x & 63;
  const int nb = blockIdx.x * 16;
  const unsigned short* Xl = T0b + l * 4;
  // phase 1: wave wv gathers rows 2wv, 2wv+1; edges via shuffle-broadcast
#pragma unroll
  for (int i = 0; i < 2; ++i) {
    const int r = wv * 2 + i;
    const int node = nb + r;
    const int r0 = rp[node], r1 = rp[node + 1];
    float acc[4] = {};
    for (int base = r0; base < r1; base += 64) {
      int m = r1 - base; if (m > 64) m = 64;
      int2 me = make_int2(0, 0);
      if (base + l < r1) me = edges[base + l];
      int j = 0;
      for (; j + 4 <= m; j += 4) {
        int s0 = __shfl(me.x, j + 0), s1 = __shfl(me.x, j + 1);
        int s2 = __shfl(me.x, j + 2), s3 = __shfl(me.x, j + 3);
        float v0 = __int_as_float(__shfl(me.y, j + 0));
        float v1 = __int_as_float(__shfl(me.y, j + 1));
        float v2 = __int_as_float(__shfl(me.y, j + 2));
        float v3 = __int_as_float(__shfl(me.y, j + 3));
        u16x4 a = *reinterpret_cast<const u16x4*>(Xl + (size_t)s0 * 256);
        u16x4 b = *reinterpret_cast<const u16x4*>(Xl + (size_t)s1 * 256);
        u16x4 c = *reinterpret_cast<const u16x4*>(Xl + (size_t)s2 * 256);
        u16x4 d = *reinterpret_cast<const u16x4*>(Xl + (size_t)s3 * 256);
#pragma unroll
        for (int q = 0; q < 4; ++q) acc[q] = fmaf(v0, bf2f(a[q]), acc[q]);
#pragma unroll
        for (int q = 0; q < 4; ++q) acc[q] = fmaf(v1, bf2f(b[q]), acc[q]);
#pragma unroll
        for (int q = 0; q < 4; ++q) acc[q] = fmaf(v2, bf2f(c[q]), acc[q]);
#pragma unroll
        for (int q = 0; q < 4; ++q) acc[q] = fmaf(v3, bf2f(d[q]), acc[q]);
      }
      for (; j < m; ++j) {
        int s0 = __shfl(me.x, j);
        float v0 = __int_as_float(__shfl(me.y, j));
        u16x4 a = *reinterpret_cast<const u16x4*>(Xl + (size_t)s0 * 256);
#pragma unroll
        for (int q = 0; q < 4; ++q) acc[q] = fmaf(v0, bf2f(a[q]), acc[q]);
      }
    }
    u16x4 o;
#pragma unroll
    for (int q = 0; q < 4; ++q) o[q] = f2bf(fmaxf(acc[q], 0.f));
    int off = (r * 512 + l * 8) ^ ((r & 7) << 4);
    *reinterpret_cast<u16x4*>(reinterpret_cast<char*>(Zs) + off) = o;
  }
  __syncthreads();
  // phase 2: wave wv computes cols [16wv, 16wv+16)
  const int row = l & 15;
  const int kof = (l >> 4) * 8;
  const int cb = wv * 16;
  f32x4 acc2 = {};
#pragma unroll
  for (int k0 = 0; k0 < 256; k0 += 32) {
    int aoff = (row * 512 + (k0 + kof) * 2) ^ ((row & 7) << 4);
    bf16x8 af = *reinterpret_cast<const bf16x8*>(reinterpret_cast<const char*>(Zs) + aoff);
    bf16x8 bfr = *reinterpret_cast<const bf16x8*>(
        W1t + (size_t)(cb + row) * 256 + k0 + kof);
    acc2 = __builtin_amdgcn_mfma_f32_16x16x32_bf16(af, bfr, acc2, 0, 0, 0);
  }
  const int orow0 = (l >> 4) * 4;
  const int col = cb + row;
#pragma unroll
  for (int rr = 0; rr < 4; ++rr)
    T1b[(size_t)(nb + orow0 + rr) * OUT_DIM + col] = f2bf(acc2[rr]);
}

// ---- final spmm: out[n,:128], half-wave per node, shuffle-broadcast edges ----
__global__ __launch_bounds__(256)
void spmm_out(const unsigned short* __restrict__ T1b,
              const int2* __restrict__ edges,
              const int* __restrict__ rp,
              float* __restrict__ out) {
  const int wv = threadIdx.x >> 6;
  const int lane = threadIdx.x & 63;
  const int half = lane >> 5;
  const int hl = lane & 31;                   // 32 lanes x 4 cols = 128
  const int node = blockIdx.x * 8 + wv * 2 + half;
  const int r0 = rp[node], r1 = rp[node + 1];
  float acc[4] = {};
  const unsigned short* Xl = T1b + hl * 4;
  for (int base = r0; base < r1; base += 32) {
    int m = r1 - base; if (m > 32) m = 32;
    int2 me = make_int2(0, 0);
    if (base + hl < r1) me = edges[base + hl];
    int j = 0;
    for (; j + 4 <= m; j += 4) {
      int s0 = __shfl(me.x, j + 0, 32), s1 = __shfl(me.x, j + 1, 32);
      int s2 = __shfl(me.x, j + 2, 32), s3 = __shfl(me.x, j + 3, 32);
      float v0 = __int_as_float(__shfl(me.y, j + 0, 32));
      float v1 = __int_as_float(__shfl(me.y, j + 1, 32));
      float v2 = __int_as_float(__shfl(me.y, j + 2, 32));
      float v3 = __int_as_float(__shfl(me.y, j + 3, 32));
      u16x4 a = *reinterpret_cast<const u16x4*>(Xl + (size_t)s0 * 128);
      u16x4 b = *reinterpret_cast<const u16x4*>(Xl + (size_t)s1 * 128);
      u16x4 c = *reinterpret_cast<const u16x4*>(Xl + (size_t)s2 * 128);
      u16x4 d = *reinterpret_cast<const u16x4*>(Xl + (size_t)s3 * 128);
#pragma unroll
      for (int q = 0; q < 4; ++q) acc[q] = fmaf(v0, bf2f(a[q]), acc[q]);
#pragma unroll
      for (int q = 0; q < 4; ++q) acc[q] = fmaf(v1, bf2f(b[q]), acc[q]);
#pragma unroll
      for (int q = 0; q < 4; ++q) acc[q] = fmaf(v2, bf2f(c[q]), acc[q]);
#pragma unroll
      for (int q = 0; q < 4; ++q) acc[q] = fmaf(v3, bf2f(d[q]), acc[q]);
    }
    for (; j < m; ++j) {
      int s0 = __shfl(me.x, j, 32);
      float v0 = __int_as_float(__shfl(me.y, j, 32));
      u16x4 a = *reinterpret_cast<const u16x4*>(Xl + (size_t)s0 * 128);
#pragma unroll
      for (int q = 0; q < 4; ++q) acc[q] = fmaf(v0, bf2f(a[q]), acc[q]);
    }
  }
  float4 o; o.x = acc[0]; o.y = acc[1]; o.z = acc[2]; o.w = acc[3];
  *reinterpret_cast<float4*>(out + (size_t)node * OUT_DIM + hl * 4) = o;
}

extern "C" void kernel_launch(void* const* d_in, const int* in_sizes, int n_in,
                              void* d_out, int out_size, void* d_ws, size_t ws_size,
                              hipStream_t stream) {
  const float* features = (const float*)d_in[0];
  const int*   esrc     = (const int*)d_in[1];
  const int*   edst     = (const int*)d_in[2];
  const float* evalv    = (const float*)d_in[3];
  const float* W0       = (const float*)d_in[4];
  const float* W1       = (const float*)d_in[5];
  const int nE = in_sizes[1];
  float* out = (float*)d_out;

  unsigned short* W0t = (unsigned short*)d_ws;                 // [256,256]
  unsigned short* W1t = W0t + (size_t)IN_DIM * HIDDEN;         // [128,256]
  unsigned short* T0b = W1t + (size_t)OUT_DIM * HIDDEN;        // [N,256]
  unsigned short* T1b = T0b + (size_t)N_NODES * HIDDEN;        // [N,128]
  int2* edges  = (int2*)(T1b + (size_t)N_NODES * OUT_DIM);     // [E]
  int* cnt     = (int*)(edges + nE);                           // [N]
  int* rowptr  = cnt + N_NODES;                                // [N+1]
  int* rowcur  = rowptr + N_NODES + 1;                         // [N]

  const int ebk = (nE + 255) / 256;

  hipMemsetAsync(cnt, 0, N_NODES * sizeof(int), stream);
  hist_convW<<<ebk, 256, 0, stream>>>(edst, cnt, W0, W1, W0t, W1t, nE);
  scan_kernel<<<1, 1024, 0, stream>>>(cnt, rowptr, rowcur);
  bucket_kernel<<<ebk, 256, 0, stream>>>(esrc, edst, evalv, rowcur, edges, nE);

  // T0b = bf16(F @ W0)
  gemm_mfma<<<dim3(HIDDEN / 64, (N_NODES + 63) / 64), 256, 0, stream>>>(features, W0t, T0b);
  // T1b = bf16(relu(A @ T0) @ W1)
  fused_spmm_gemm<<<N_NODES / 16, 512, 0, stream>>>(T0b, edges, rowptr, W1t, T1b);
  // out = A @ T1
  spmm_out<<<N_NODES / 8, 256, 0, stream>>>(T1b, edges, rowptr, out);
}